// Round 3
// baseline (509.884 us; speedup 1.0000x reference)
//
#include <hip/hip_runtime.h>
#include <cstdint>

#define B_ 4
#define S_ 2048
#define D_ 512
#define H_ 8
#define DK_ 64
#define SCALE 0.125f
#define KSTR 84   // K/V LDS row stride in bf16 (measured conflict-free)
#define PSTR 68   // Ps LDS row stride in bf16 (measured conflict-free)

using bfrag = __attribute__((ext_vector_type(8))) __bf16;
using b4    = __attribute__((ext_vector_type(4))) __bf16;
using f4    = __attribute__((ext_vector_type(4))) float;
using f16v  = __attribute__((ext_vector_type(16))) float;

#define MFMA16(a, b, c) __builtin_amdgcn_mfma_f32_16x16x32_bf16(a, b, c, 0, 0, 0)
#define MFMA32(a, b, c) __builtin_amdgcn_mfma_f32_32x32x16_bf16(a, b, c, 0, 0, 0)

// ---------------------------------------------------------------------------
// All 4 weight transposes in one launch: grid (1024, 4).
// ---------------------------------------------------------------------------
__global__ __launch_bounds__(256) void wtr_all(
    const float* __restrict__ Wqkv, const float* __restrict__ Wout,
    __bf16* __restrict__ WqTh, __bf16* __restrict__ WqTl,
    __bf16* __restrict__ WkTh, __bf16* __restrict__ WkTl,
    __bf16* __restrict__ WvTh, __bf16* __restrict__ WoTh) {
  const int by = blockIdx.y;
  const int idx = blockIdx.x * 256 + threadIdx.x;  // 512*512
  const int k = idx & 511, n = idx >> 9;
  const float* W = (by == 3) ? Wout : Wqkv;
  const int ldw = (by == 3) ? 512 : 1536;
  const int c0 = (by == 3) ? 0 : by * 512;
  const float x = W[(size_t)k * ldw + c0 + n];
  const __bf16 h = (__bf16)x;
  __bf16* th = (by == 0) ? WqTh : (by == 1) ? WkTh : (by == 2) ? WvTh : WoTh;
  th[(size_t)n * 512 + k] = h;
  if (by < 2) {
    __bf16* tl = (by == 0) ? WqTl : WkTl;
    tl[(size_t)n * 512 + k] = (__bf16)(x - (float)h);
  }
}

// ---------------------------------------------------------------------------
// Split-bf16 MFMA GEMM (unchanged — verified in prior rounds).
// ---------------------------------------------------------------------------
template <bool AF32, bool BF32, bool LO, int MODE>
__global__ __launch_bounds__(256) void gemm_mfma(
    const void* __restrict__ Ap, const void* __restrict__ Bp, const void* __restrict__ Blop,
    float* __restrict__ Cf, __bf16* __restrict__ Oh, __bf16* __restrict__ Ol) {
  __shared__ __bf16 Ash[64 * 40];
  __shared__ __bf16 Asl[64 * 40];
  __shared__ __bf16 Bsh[64 * 40];
  __shared__ __bf16 Bsl[64 * 40];

  const int tid = threadIdx.x;
  const int m0 = blockIdx.y * 64, n0 = blockIdx.x * 64;
  const int row = tid >> 2, seg = tid & 3;
  const int lane = tid & 63, wv = tid >> 6;
  const int wm = (wv & 1) * 32, wn = (wv >> 1) * 32;
  const int qd = lane >> 4, ln = lane & 15;

  f4 acc[2][2];
#pragma unroll
  for (int i = 0; i < 2; i++)
#pragma unroll
    for (int j = 0; j < 2; j++)
#pragma unroll
      for (int r = 0; r < 4; r++) acc[i][j][r] = 0.f;

  for (int kt = 0; kt < 512; kt += 32) {
    const size_t abase = (size_t)(m0 + row) * 512 + kt + seg * 8;
    const size_t bbase = (size_t)(n0 + row) * 512 + kt + seg * 8;
    float4 a0, a1, b0, b1, bl0;
    if constexpr (AF32) {
      const float* A = (const float*)Ap;
      a0 = *(const float4*)&A[abase];
      a1 = *(const float4*)&A[abase + 4];
    } else {
      const __bf16* A = (const __bf16*)Ap;
      a0 = *(const float4*)&A[abase];
    }
    if constexpr (BF32) {
      const float* Bm = (const float*)Bp;
      b0 = *(const float4*)&Bm[bbase];
      b1 = *(const float4*)&Bm[bbase + 4];
    } else {
      const __bf16* Bm = (const __bf16*)Bp;
      b0 = *(const float4*)&Bm[bbase];
      if constexpr (LO) {
        const __bf16* Bl = (const __bf16*)Blop;
        bl0 = *(const float4*)&Bl[bbase];
      }
    }
    __syncthreads();
    if constexpr (AF32) {
      float x[8] = {a0.x, a0.y, a0.z, a0.w, a1.x, a1.y, a1.z, a1.w};
      bfrag h, l;
#pragma unroll
      for (int j = 0; j < 8; j++) {
        h[j] = (__bf16)x[j];
        l[j] = (__bf16)(x[j] - (float)h[j]);
      }
      *(bfrag*)&Ash[row * 40 + seg * 8] = h;
      if constexpr (LO) *(bfrag*)&Asl[row * 40 + seg * 8] = l;
    } else {
      *(float4*)&Ash[row * 40 + seg * 8] = a0;
    }
    if constexpr (BF32) {
      float x[8] = {b0.x, b0.y, b0.z, b0.w, b1.x, b1.y, b1.z, b1.w};
      bfrag h;
#pragma unroll
      for (int j = 0; j < 8; j++) h[j] = (__bf16)x[j];
      *(bfrag*)&Bsh[row * 40 + seg * 8] = h;
    } else {
      *(float4*)&Bsh[row * 40 + seg * 8] = b0;
      if constexpr (LO) *(float4*)&Bsl[row * 40 + seg * 8] = bl0;
    }
    __syncthreads();

    bfrag ah[2], al[2], bh[2], bl[2];
#pragma unroll
    for (int mi = 0; mi < 2; mi++) {
      ah[mi] = *(bfrag*)&Ash[(wm + mi * 16 + ln) * 40 + qd * 8];
      if constexpr (LO) al[mi] = *(bfrag*)&Asl[(wm + mi * 16 + ln) * 40 + qd * 8];
    }
#pragma unroll
    for (int ni = 0; ni < 2; ni++) {
      bh[ni] = *(bfrag*)&Bsh[(wn + ni * 16 + ln) * 40 + qd * 8];
      if constexpr (LO) bl[ni] = *(bfrag*)&Bsl[(wn + ni * 16 + ln) * 40 + qd * 8];
    }
#pragma unroll
    for (int mi = 0; mi < 2; mi++)
#pragma unroll
      for (int ni = 0; ni < 2; ni++) {
        acc[mi][ni] = MFMA16(ah[mi], bh[ni], acc[mi][ni]);
        if constexpr (LO) {
          acc[mi][ni] = MFMA16(ah[mi], bl[ni], acc[mi][ni]);
          acc[mi][ni] = MFMA16(al[mi], bh[ni], acc[mi][ni]);
        }
      }
  }

#pragma unroll
  for (int mi = 0; mi < 2; mi++)
#pragma unroll
    for (int ni = 0; ni < 2; ni++)
#pragma unroll
      for (int r = 0; r < 4; r++) {
        const int mrow = m0 + wm + mi * 16 + qd * 4 + r;
        const int ncol = n0 + wn + ni * 16 + ln;
        const float c = acc[mi][ni][r];
        if constexpr (MODE == 0) {
          Cf[(size_t)mrow * 512 + ncol] = c;
        } else if constexpr (MODE == 1) {
          const int b = mrow >> 11, s = mrow & (S_ - 1);
          const int h = ncol >> 6, dk = ncol & 63;
          const size_t o = (((size_t)b * H_ + h) * S_ + s) * DK_ + dk;
          __bf16 hh = (__bf16)c;
          Oh[o] = hh;
          Ol[o] = (__bf16)(c - (float)hh);
        } else {  // MODE 2: V^T
          const int h = mrow >> 6, dk = mrow & 63;
          const int b = ncol >> 11, s = ncol & (S_ - 1);
          Oh[(((size_t)b * H_ + h) * DK_ + dk) * S_ + s] = (__bf16)c;
        }
      }
}

// ---------------------------------------------------------------------------
// Fused flash attention — KV-SPLIT x2 + LDS ALIASING for occupancy.
// R2 post-mortem: 1024 blocks at LDS=50176 still placed only 2 blocks/CU
// (usable workgroup-LDS pool behaves like 128 KiB). Fix: Ps aliases the
// Ksh/Ksl region (K is register-consumed into z before Ps is written; one
// extra __syncthreads() between last K read and first Ps write prevents the
// cross-wave race). LDS: union(K,Ps) 21504 + Vs 10752 + als 512 = 32768 B
// -> 4 blocks/CU (= VGPR cap at 120 regs), 16 waves/CU, and the kv-split's
// 1024 blocks = exactly 4/CU.
// Ps/als consumers are wave-private rows -> no additional syncs needed.
// ---------------------------------------------------------------------------
__global__ __launch_bounds__(256) void attn_fctx(
    const __bf16* __restrict__ Qh_, const __bf16* __restrict__ Ql_,
    const __bf16* __restrict__ Kh_, const __bf16* __restrict__ Kl_,
    const __bf16* __restrict__ VT, const float* __restrict__ mask,
    __bf16* __restrict__ CTXp, float* __restrict__ Mp, float* __restrict__ Lp,
    __bf16* __restrict__ E, float* __restrict__ MT) {
  __shared__ __bf16 KPs[64 * KSTR * 2];   // Ksh [0,5376), Ksl [5376,10752); Ps aliases [0,8704)
  __shared__ __bf16 Vs[64 * KSTR];
  __shared__ float als[128];
  __bf16* const Ksh = KPs;
  __bf16* const Ksl = KPs + 64 * KSTR;
  __bf16* const Ps  = KPs;

  const int tid = threadIdx.x, lane = tid & 63, wv = tid >> 6;
  const int l31 = lane & 31, kh = lane >> 5;
  const int qd = lane >> 4, ln = lane & 15;
  const int bh = blockIdx.y;
  const int q0b = blockIdx.x * 128;
  const int q0w = q0b + wv * 32;
  const int srow = tid >> 2, sseg = tid & 3;
  const int kv0 = blockIdx.z << 10;  // 0 or 1024

  // Q fragments (B-operand, 32x32x16): n = q = l31, k = ks*16 + kh*8 + j
  bfrag qhf[4], qlf[4];
#pragma unroll
  for (int ks = 0; ks < 4; ks++) {
    const size_t qb = ((size_t)bh * S_ + q0w + l31) * DK_ + ks * 16 + kh * 8;
    qhf[ks] = *(const bfrag*)&Qh_[qb];
    qlf[ks] = *(const bfrag*)&Ql_[qb];
  }

  float m = -3.0e38f, l = 0.f;   // per lane: q = q0w + l31 (dup across halves)
  f4 cacc[2][4];                  // [mt][nt] — PV 16-shape accumulators
#pragma unroll
  for (int mt = 0; mt < 2; mt++)
#pragma unroll
    for (int nt = 0; nt < 4; nt++)
#pragma unroll
      for (int r = 0; r < 4; r++) cacc[mt][nt][r] = 0.f;

  // prefetch tile 0 of this part
  float4 h0, h1, l0, l1, v0, v1;
  {
    const size_t kb = ((size_t)bh * S_ + kv0 + srow) * DK_ + sseg * 16;
    const size_t vb = ((size_t)bh * DK_ + srow) * S_ + kv0 + sseg * 16;
    h0 = *(const float4*)&Kh_[kb]; h1 = *(const float4*)&Kh_[kb + 8];
    l0 = *(const float4*)&Kl_[kb]; l1 = *(const float4*)&Kl_[kb + 8];
    v0 = *(const float4*)&VT[vb];  v1 = *(const float4*)&VT[vb + 8];
  }

  for (int kt = kv0; kt < kv0 + 1024; kt += 64) {
    __syncthreads();   // previous tile's Ps/Vs reads done -> safe to overwrite
    *(float4*)&Ksh[srow * KSTR + sseg * 16] = h0;
    *(float4*)&Ksh[srow * KSTR + sseg * 16 + 8] = h1;
    *(float4*)&Ksl[srow * KSTR + sseg * 16] = l0;
    *(float4*)&Ksl[srow * KSTR + sseg * 16 + 8] = l1;
    *(float4*)&Vs[srow * KSTR + sseg * 16] = v0;
    *(float4*)&Vs[srow * KSTR + sseg * 16 + 8] = v1;
    __syncthreads();

    // mask, transposed order: entry (q = q0w+l31, kv = kt + t*32 + g*8 + 4*kh + i)
    f4 mk[2][4];
#pragma unroll
    for (int t = 0; t < 2; t++)
#pragma unroll
      for (int g = 0; g < 4; g++)
        mk[t][g] = *(const f4*)&mask[(size_t)(q0w + l31) * S_ + kt + t * 32 + g * 8 + 4 * kh];

    // prefetch next tile
    if (kt + 64 < kv0 + 1024) {
      const size_t kb = ((size_t)bh * S_ + kt + 64 + srow) * DK_ + sseg * 16;
      const size_t vb = ((size_t)bh * DK_ + srow) * S_ + kt + 64 + sseg * 16;
      h0 = *(const float4*)&Kh_[kb]; h1 = *(const float4*)&Kh_[kb + 8];
      l0 = *(const float4*)&Kl_[kb]; l1 = *(const float4*)&Kl_[kb + 8];
      v0 = *(const float4*)&VT[vb];  v1 = *(const float4*)&VT[vb + 8];
    }

    // ---- z^T = K·Q^T, 32x32x16 split-3: 16 b128 reads, 24 MFMAs, 32 q ----
    f16v z[2];
#pragma unroll
    for (int t = 0; t < 2; t++)
#pragma unroll
      for (int r = 0; r < 16; r++) z[t][r] = 0.f;
#pragma unroll
    for (int t = 0; t < 2; t++)
#pragma unroll
      for (int ks = 0; ks < 4; ks++) {
        bfrag kbh = *(bfrag*)&Ksh[(t * 32 + l31) * KSTR + ks * 16 + kh * 8];
        bfrag kbl = *(bfrag*)&Ksl[(t * 32 + l31) * KSTR + ks * 16 + kh * 8];
        z[t] = MFMA32(kbh, qhf[ks], z[t]);
        z[t] = MFMA32(kbl, qhf[ks], z[t]);
        z[t] = MFMA32(kbh, qlf[ks], z[t]);
      }

    // ---- scale + mask in place ----
#pragma unroll
    for (int t = 0; t < 2; t++)
#pragma unroll
      for (int r = 0; r < 16; r++)
        z[t][r] = fmaf(z[t][r], SCALE, mk[t][r >> 2][r & 3]);

    // ---- online softmax: per-lane q column, 1 cross-lane reduce ----
    float tm = z[0][0];
#pragma unroll
    for (int t = 0; t < 2; t++)
#pragma unroll
      for (int r = 0; r < 16; r++) tm = fmaxf(tm, z[t][r]);
    tm = fmaxf(tm, __shfl_xor(tm, 32, 64));
    const float nm = fmaxf(m, tm);
    const float al = __expf(m - nm);
    m = nm;
    if (lane < 32) als[wv * 32 + lane] = al;

    __syncthreads();   // all waves done reading Ksh/Ksl -> Ps may overwrite

    float ls = 0.f;
#pragma unroll
    for (int t = 0; t < 2; t++)
#pragma unroll
      for (int g = 0; g < 4; g++) {
        const float e0 = __expf(z[t][g * 4 + 0] - nm);
        const float e1 = __expf(z[t][g * 4 + 1] - nm);
        const float e2 = __expf(z[t][g * 4 + 2] - nm);
        const float e3 = __expf(z[t][g * 4 + 3] - nm);
        ls += (e0 + e1) + (e2 + e3);
        b4 pk;
        pk[0] = (__bf16)e0; pk[1] = (__bf16)e1;
        pk[2] = (__bf16)e2; pk[3] = (__bf16)e3;
        *(b4*)&Ps[(wv * 32 + l31) * PSTR + t * 32 + g * 8 + 4 * kh] = pk;
      }
    l = l * al + ls;

    if (lane < 32)
      MT[((size_t)bh * 32 + (kt >> 6)) * S_ + q0w + lane] = m;

    // ---- rescale cacc with alpha from LDS (row q = mt*16 + qd*4 + r) ----
#pragma unroll
    for (int mt = 0; mt < 2; mt++) {
      f4 av = *(f4*)&als[wv * 32 + mt * 16 + qd * 4];
#pragma unroll
      for (int nt = 0; nt < 4; nt++)
#pragma unroll
        for (int r = 0; r < 4; r++) cacc[mt][nt][r] *= av[r];
    }

    // ---- PV (16 MFMA, 16-shape): P m=q (2 tiles), V n=d (4 tiles), k=kv ----
    bfrag pa[2][2];
#pragma unroll
    for (int mt = 0; mt < 2; mt++)
#pragma unroll
      for (int ks = 0; ks < 2; ks++)
        pa[mt][ks] = *(bfrag*)&Ps[(wv * 32 + mt * 16 + ln) * PSTR + ks * 32 + qd * 8];
#pragma unroll
    for (int nt = 0; nt < 4; nt++)
#pragma unroll
      for (int ks = 0; ks < 2; ks++) {
        bfrag vbf = *(bfrag*)&Vs[(nt * 16 + ln) * KSTR + ks * 32 + qd * 8];
#pragma unroll
        for (int mt = 0; mt < 2; mt++)
          cacc[mt][nt] = MFMA16(pa[mt][ks], vbf, cacc[mt][nt]);
      }

    // ---- E copy: wave-private Ps rows -> global (vectorized, coalesced) ----
#pragma unroll
    for (int c = 0; c < 4; c++) {
      const int row = wv * 32 + (lane >> 3) + c * 8;
      const int ch = lane & 7;
      f4 ev = *(f4*)&Ps[row * PSTR + ch * 8];
      __builtin_nontemporal_store(
          ev, (f4*)&E[((size_t)bh * S_ + q0b + row) * S_ + kt + ch * 8]);
    }
  }

  // ---- epilogue: write PARTIAL (unnormalized ctx, m, l) for this kv half ----
  l += __shfl_xor(l, 32, 64);
  const size_t pofs = (size_t)blockIdx.z * ((size_t)B_ * H_ * S_);
  if (lane < 32) {
    Mp[pofs + (size_t)bh * S_ + q0w + lane] = m;
    Lp[pofs + (size_t)bh * S_ + q0w + lane] = l;
  }
#pragma unroll
  for (int mt = 0; mt < 2; mt++)
#pragma unroll
    for (int nt = 0; nt < 4; nt++)
#pragma unroll
      for (int r = 0; r < 4; r++)
        CTXp[(pofs + (size_t)bh * S_ + q0w + mt * 16 + qd * 4 + r) * DK_ + nt * 16 + ln] =
            (__bf16)cacc[mt][nt][r];
}

// ---------------------------------------------------------------------------
// Combine the two kv-half partials: ctx = (c0*e0 + c1*e1)/l_fin, and write
// final MR/LR for mean_rescale. One thread per 4 dk elements.
// Grid: B*H*S*16/256 = 4096 blocks.
// ---------------------------------------------------------------------------
__global__ __launch_bounds__(256) void ctx_combine(
    const __bf16* __restrict__ CTXp, const float* __restrict__ Mp,
    const float* __restrict__ Lp, __bf16* __restrict__ CTXb,
    float* __restrict__ MR, float* __restrict__ LR) {
  const size_t gid = (size_t)blockIdx.x * 256 + threadIdx.x;
  const size_t row = gid >> 4;               // bh*S + s, in [0, B*H*S)
  const int c4 = (int)(gid & 15) * 4;
  const size_t NR = (size_t)B_ * H_ * S_;
  const float m0 = Mp[row], m1 = Mp[NR + row];
  const float l0 = Lp[row], l1 = Lp[NR + row];
  const float m = fmaxf(m0, m1);
  const float e0 = __expf(m0 - m), e1 = __expf(m1 - m);
  const float lf = fmaf(l0, e0, l1 * e1);
  const float inv = 1.0f / lf;
  if (c4 == 0) { MR[row] = m; LR[row] = lf; }
  const b4 a = *(const b4*)&CTXp[row * DK_ + c4];
  const b4 bv = *(const b4*)&CTXp[(NR + row) * DK_ + c4];
  const int bh = (int)(row >> 11);           // S = 2048
  const int s = (int)(row & (S_ - 1));
  const int b = bh >> 3, h = bh & 7;
  b4 ov;
#pragma unroll
  for (int j = 0; j < 4; j++)
    ov[j] = (__bf16)((((float)a[j]) * e0 + ((float)bv[j]) * e1) * inv);
  *(b4*)&CTXb[((size_t)b * S_ + s) * D_ + h * DK_ + c4] = ov;
}

// ---------------------------------------------------------------------------
// mean = (1/8) sum_h E * exp(MT - m_fin) / l_fin  — bandwidth kernel.
// (unchanged — verified). NOTE: overwrites the scratch region that held
// CXp/Mp/Lp; runs after ctx_combine, so this is safe.
// ---------------------------------------------------------------------------
__global__ __launch_bounds__(256) void mean_rescale(
    const __bf16* __restrict__ E, const float* __restrict__ MT,
    const float* __restrict__ MR, const float* __restrict__ LR,
    float* __restrict__ meanout) {
  const int t = threadIdx.x;
  const int qr = t >> 3, seg = t & 7;
  const int b = blockIdx.y, ks = blockIdx.z;
  const int qg = blockIdx.x * 32 + qr;

  float mf[H_], il[H_];
#pragma unroll
  for (int h = 0; h < H_; h++) {
    const int bh = b * H_ + h;
    mf[h] = MR[(size_t)bh * S_ + qg];
    il[h] = 1.0f / LR[(size_t)bh * S_ + qg];
  }

  for (int kc = 0; kc < 8; kc++) {
    const int k0 = ks * 512 + kc * 64;
    const int tk = k0 >> 6;
    float acc[8];
#pragma unroll
    for (int j = 0; j < 8; j++) acc[j] = 0.f;
#pragma unroll
    for (int h = 0; h < H_; h++) {
      const int bh = b * H_ + h;
      const float mt = MT[((size_t)bh * 32 + tk) * S_ + qg];
      const float sc = __expf(mt - mf[h]) * il[h];
      bfrag e = __builtin_nontemporal_load(
          (const bfrag*)&E[((size_t)bh * S_ + qg) * S_ + k0 + seg * 8]);
#pragma unroll
      for (int j = 0; j < 8; j++) acc[j] += (float)e[j] * sc;
    }
    f4 o0, o1;
    o0[0] = acc[0] * 0.125f; o0[1] = acc[1] * 0.125f;
    o0[2] = acc[2] * 0.125f; o0[3] = acc[3] * 0.125f;
    o1[0] = acc[4] * 0.125f; o1[1] = acc[5] * 0.125f;
    o1[2] = acc[6] * 0.125f; o1[3] = acc[7] * 0.125f;
    float* mp = &meanout[((size_t)b * S_ + qg) * S_ + k0 + seg * 8];
    *(f4*)&mp[0] = o0;
    *(f4*)&mp[4] = o1;
  }
}

// ---------------------------------------------------------------------------
extern "C" void kernel_launch(void* const* d_in, const int* in_sizes, int n_in,
                              void* d_out, int out_size, void* d_ws, size_t ws_size,
                              hipStream_t stream) {
  (void)in_sizes; (void)n_in; (void)out_size; (void)ws_size;
  const float* Zq = (const float*)d_in[0];
  const float* Zkv = (const float*)d_in[1];
  const float* mask = (const float*)d_in[2];
  const float* Wqkv = (const float*)d_in[3];
  const float* Wout = (const float*)d_in[4];

  float* out = (float*)d_out;                // [B,S,D]
  float* mean = out + (size_t)B_ * S_ * D_;  // [B,S,S]

  char* w = (char*)d_ws;
  const size_t WSZ = 512 * 512 * sizeof(__bf16);
  const size_t QSZ = (size_t)B_ * H_ * S_ * DK_ * sizeof(__bf16);
  const size_t RSZ = (size_t)B_ * H_ * S_ * sizeof(float);
  __bf16* WqTh = (__bf16*)w; w += WSZ;
  __bf16* WqTl = (__bf16*)w; w += WSZ;
  __bf16* WkTh = (__bf16*)w; w += WSZ;
  __bf16* WkTl = (__bf16*)w; w += WSZ;
  __bf16* WvTh = (__bf16*)w; w += WSZ;
  __bf16* WoTh = (__bf16*)w; w += WSZ;
  __bf16* Qh = (__bf16*)w; w += QSZ;
  __bf16* Ql = (__bf16*)w; w += QSZ;
  __bf16* Kh = (__bf16*)w; w += QSZ;
  __bf16* Kl = (__bf16*)w; w += QSZ;
  __bf16* VTh = (__bf16*)w; w += QSZ;
  __bf16* CTXb = (__bf16*)w; w += QSZ;
  float* MR = (float*)w; w += RSZ;
  float* LR = (float*)w; w += RSZ;
  float* MT = (float*)w; w += (size_t)B_ * H_ * 32 * S_ * sizeof(float);   // 8.4 MB
  __bf16* E = (__bf16*)w; w += (size_t)B_ * H_ * S_ * S_ * sizeof(__bf16); // 268 MB
  // --- kv-split partials: scratch carved from the MEAN OUTPUT region ---
  // mean is 67 MB, written only by mean_rescale (after ctx_combine), so the
  // first 17.8 MB serve as stream-ordered scratch. Zero workspace growth.
  char* scr = (char*)mean;
  __bf16* CXp = (__bf16*)scr; scr += 2 * QSZ;   // 16.8 MB
  float* Mp = (float*)scr; scr += 2 * RSZ;      // 0.5 MB
  float* Lp = (float*)scr; scr += 2 * RSZ;      // 0.5 MB

  wtr_all<<<dim3(1024, 4), 256, 0, stream>>>(Wqkv, Wout, WqTh, WqTl, WkTh, WkTl, WvTh, WoTh);

  gemm_mfma<true, false, true, 1><<<dim3(8, 128), 256, 0, stream>>>(
      Zq, WqTh, WqTl, nullptr, Qh, Ql);
  gemm_mfma<true, false, true, 1><<<dim3(8, 128), 256, 0, stream>>>(
      Zkv, WkTh, WkTl, nullptr, Kh, Kl);
  gemm_mfma<false, true, false, 2><<<dim3(128, 8), 256, 0, stream>>>(
      WvTh, Zkv, nullptr, nullptr, VTh, nullptr);

  attn_fctx<<<dim3(16, 32, 2), 256, 0, stream>>>(Qh, Ql, Kh, Kl, VTh, mask, CXp, Mp, Lp, E, MT);
  ctx_combine<<<dim3(4096), 256, 0, stream>>>(CXp, Mp, Lp, CTXb, MR, LR);
  mean_rescale<<<dim3(64, 4, 4), 256, 0, stream>>>(E, MT, MR, LR, mean);

  gemm_mfma<false, false, false, 0><<<dim3(8, 128), 256, 0, stream>>>(
      CTXb, WoTh, nullptr, out, nullptr, nullptr);
}

// Round 4
// 379.703 us; speedup vs baseline: 1.3428x; 1.3428x over previous
//
#include <hip/hip_runtime.h>
#include <cstdint>

#define B_ 4
#define S_ 2048
#define D_ 512
#define H_ 8
#define DK_ 64
#define SCALE 0.125f
#define KSTR 84   // K/V LDS row stride in bf16 (measured conflict-free)
#define PSTR 68   // Ps LDS row stride in bf16 (measured conflict-free)

using bfrag = __attribute__((ext_vector_type(8))) __bf16;
using b4    = __attribute__((ext_vector_type(4))) __bf16;
using f4    = __attribute__((ext_vector_type(4))) float;
using f2    = __attribute__((ext_vector_type(2))) float;
using f16v  = __attribute__((ext_vector_type(16))) float;
using u2    = __attribute__((ext_vector_type(2))) unsigned int;

#define MFMA16(a, b, c) __builtin_amdgcn_mfma_f32_16x16x32_bf16(a, b, c, 0, 0, 0)
#define MFMA32(a, b, c) __builtin_amdgcn_mfma_f32_32x32x16_bf16(a, b, c, 0, 0, 0)

// ---------------------------------------------------------------------------
// All 4 weight transposes in one launch: grid (1024, 4).
// ---------------------------------------------------------------------------
__global__ __launch_bounds__(256) void wtr_all(
    const float* __restrict__ Wqkv, const float* __restrict__ Wout,
    __bf16* __restrict__ WqTh, __bf16* __restrict__ WqTl,
    __bf16* __restrict__ WkTh, __bf16* __restrict__ WkTl,
    __bf16* __restrict__ WvTh, __bf16* __restrict__ WoTh) {
  const int by = blockIdx.y;
  const int idx = blockIdx.x * 256 + threadIdx.x;  // 512*512
  const int k = idx & 511, n = idx >> 9;
  const float* W = (by == 3) ? Wout : Wqkv;
  const int ldw = (by == 3) ? 512 : 1536;
  const int c0 = (by == 3) ? 0 : by * 512;
  const float x = W[(size_t)k * ldw + c0 + n];
  const __bf16 h = (__bf16)x;
  __bf16* th = (by == 0) ? WqTh : (by == 1) ? WkTh : (by == 2) ? WvTh : WoTh;
  th[(size_t)n * 512 + k] = h;
  if (by < 2) {
    __bf16* tl = (by == 0) ? WqTl : WkTl;
    tl[(size_t)n * 512 + k] = (__bf16)(x - (float)h);
  }
}

// ---------------------------------------------------------------------------
// Split-bf16 MFMA GEMM (unchanged — verified in prior rounds).
// ---------------------------------------------------------------------------
template <bool AF32, bool BF32, bool LO, int MODE>
__global__ __launch_bounds__(256) void gemm_mfma(
    const void* __restrict__ Ap, const void* __restrict__ Bp, const void* __restrict__ Blop,
    float* __restrict__ Cf, __bf16* __restrict__ Oh, __bf16* __restrict__ Ol) {
  __shared__ __bf16 Ash[64 * 40];
  __shared__ __bf16 Asl[64 * 40];
  __shared__ __bf16 Bsh[64 * 40];
  __shared__ __bf16 Bsl[64 * 40];

  const int tid = threadIdx.x;
  const int m0 = blockIdx.y * 64, n0 = blockIdx.x * 64;
  const int row = tid >> 2, seg = tid & 3;
  const int lane = tid & 63, wv = tid >> 6;
  const int wm = (wv & 1) * 32, wn = (wv >> 1) * 32;
  const int qd = lane >> 4, ln = lane & 15;

  f4 acc[2][2];
#pragma unroll
  for (int i = 0; i < 2; i++)
#pragma unroll
    for (int j = 0; j < 2; j++)
#pragma unroll
      for (int r = 0; r < 4; r++) acc[i][j][r] = 0.f;

  for (int kt = 0; kt < 512; kt += 32) {
    const size_t abase = (size_t)(m0 + row) * 512 + kt + seg * 8;
    const size_t bbase = (size_t)(n0 + row) * 512 + kt + seg * 8;
    float4 a0, a1, b0, b1, bl0;
    if constexpr (AF32) {
      const float* A = (const float*)Ap;
      a0 = *(const float4*)&A[abase];
      a1 = *(const float4*)&A[abase + 4];
    } else {
      const __bf16* A = (const __bf16*)Ap;
      a0 = *(const float4*)&A[abase];
    }
    if constexpr (BF32) {
      const float* Bm = (const float*)Bp;
      b0 = *(const float4*)&Bm[bbase];
      b1 = *(const float4*)&Bm[bbase + 4];
    } else {
      const __bf16* Bm = (const __bf16*)Bp;
      b0 = *(const float4*)&Bm[bbase];
      if constexpr (LO) {
        const __bf16* Bl = (const __bf16*)Blop;
        bl0 = *(const float4*)&Bl[bbase];
      }
    }
    __syncthreads();
    if constexpr (AF32) {
      float x[8] = {a0.x, a0.y, a0.z, a0.w, a1.x, a1.y, a1.z, a1.w};
      bfrag h, l;
#pragma unroll
      for (int j = 0; j < 8; j++) {
        h[j] = (__bf16)x[j];
        l[j] = (__bf16)(x[j] - (float)h[j]);
      }
      *(bfrag*)&Ash[row * 40 + seg * 8] = h;
      if constexpr (LO) *(bfrag*)&Asl[row * 40 + seg * 8] = l;
    } else {
      *(float4*)&Ash[row * 40 + seg * 8] = a0;
    }
    if constexpr (BF32) {
      float x[8] = {b0.x, b0.y, b0.z, b0.w, b1.x, b1.y, b1.z, b1.w};
      bfrag h;
#pragma unroll
      for (int j = 0; j < 8; j++) h[j] = (__bf16)x[j];
      *(bfrag*)&Bsh[row * 40 + seg * 8] = h;
    } else {
      *(float4*)&Bsh[row * 40 + seg * 8] = b0;
      if constexpr (LO) *(float4*)&Bsl[row * 40 + seg * 8] = bl0;
    }
    __syncthreads();

    bfrag ah[2], al[2], bh[2], bl[2];
#pragma unroll
    for (int mi = 0; mi < 2; mi++) {
      ah[mi] = *(bfrag*)&Ash[(wm + mi * 16 + ln) * 40 + qd * 8];
      if constexpr (LO) al[mi] = *(bfrag*)&Asl[(wm + mi * 16 + ln) * 40 + qd * 8];
    }
#pragma unroll
    for (int ni = 0; ni < 2; ni++) {
      bh[ni] = *(bfrag*)&Bsh[(wn + ni * 16 + ln) * 40 + qd * 8];
      if constexpr (LO) bl[ni] = *(bfrag*)&Bsl[(wn + ni * 16 + ln) * 40 + qd * 8];
    }
#pragma unroll
    for (int mi = 0; mi < 2; mi++)
#pragma unroll
      for (int ni = 0; ni < 2; ni++) {
        acc[mi][ni] = MFMA16(ah[mi], bh[ni], acc[mi][ni]);
        if constexpr (LO) {
          acc[mi][ni] = MFMA16(ah[mi], bl[ni], acc[mi][ni]);
          acc[mi][ni] = MFMA16(al[mi], bh[ni], acc[mi][ni]);
        }
      }
  }

#pragma unroll
  for (int mi = 0; mi < 2; mi++)
#pragma unroll
    for (int ni = 0; ni < 2; ni++)
#pragma unroll
      for (int r = 0; r < 4; r++) {
        const int mrow = m0 + wm + mi * 16 + qd * 4 + r;
        const int ncol = n0 + wn + ni * 16 + ln;
        const float c = acc[mi][ni][r];
        if constexpr (MODE == 0) {
          Cf[(size_t)mrow * 512 + ncol] = c;
        } else if constexpr (MODE == 1) {
          const int b = mrow >> 11, s = mrow & (S_ - 1);
          const int h = ncol >> 6, dk = ncol & 63;
          const size_t o = (((size_t)b * H_ + h) * S_ + s) * DK_ + dk;
          __bf16 hh = (__bf16)c;
          Oh[o] = hh;
          Ol[o] = (__bf16)(c - (float)hh);
        } else {  // MODE 2: V^T
          const int h = mrow >> 6, dk = mrow & 63;
          const int b = ncol >> 11, s = ncol & (S_ - 1);
          Oh[(((size_t)b * H_ + h) * DK_ + dk) * S_ + s] = (__bf16)c;
        }
      }
}

// ---------------------------------------------------------------------------
// Fused flash attention — R0 structure restored (best measured).
// R2/R3 lessons: occupancy is pinned at ~2 blocks/CU regardless of LDS
// (50KB->32KB: no change), and extra per-tile barriers halve all pipes.
// So: 2 barriers/tile, grid (S/128, B*H), direct CTXb/MR/LR epilogue.
// NEW vs R0: E is stored as fp8 e4m3 (hw cvt_pk), halving the 536 MB
// E round-trip (attn write + mean_rescale read). P=exp(z-m) in (0,1] is
// ideal for e4m3; out path unaffected (ctx uses bf16 Ps from LDS).
// ---------------------------------------------------------------------------
__global__ __launch_bounds__(256) void attn_fctx(
    const __bf16* __restrict__ Qh_, const __bf16* __restrict__ Ql_,
    const __bf16* __restrict__ Kh_, const __bf16* __restrict__ Kl_,
    const __bf16* __restrict__ VT, const float* __restrict__ mask,
    __bf16* __restrict__ CTXb, float* __restrict__ MR, float* __restrict__ LR,
    unsigned char* __restrict__ E, float* __restrict__ MT) {
  __shared__ __bf16 Ksh[64 * KSTR];
  __shared__ __bf16 Ksl[64 * KSTR];
  __shared__ __bf16 Vs[64 * KSTR];
  __shared__ __bf16 Ps[128 * PSTR];
  __shared__ float als[128];
  const int tid = threadIdx.x, lane = tid & 63, wv = tid >> 6;
  const int l31 = lane & 31, kh = lane >> 5;
  const int qd = lane >> 4, ln = lane & 15;
  const int bh = blockIdx.y;
  const int q0b = blockIdx.x * 128;
  const int q0w = q0b + wv * 32;
  const int srow = tid >> 2, sseg = tid & 3;

  // Q fragments (B-operand, 32x32x16): n = q = l31, k = ks*16 + kh*8 + j
  bfrag qhf[4], qlf[4];
#pragma unroll
  for (int ks = 0; ks < 4; ks++) {
    const size_t qb = ((size_t)bh * S_ + q0w + l31) * DK_ + ks * 16 + kh * 8;
    qhf[ks] = *(const bfrag*)&Qh_[qb];
    qlf[ks] = *(const bfrag*)&Ql_[qb];
  }

  float m = -3.0e38f, l = 0.f;   // per lane: q = q0w + l31 (dup across halves)
  f4 cacc[2][4];                  // [mt][nt] — PV 16-shape accumulators
#pragma unroll
  for (int mt = 0; mt < 2; mt++)
#pragma unroll
    for (int nt = 0; nt < 4; nt++)
#pragma unroll
      for (int r = 0; r < 4; r++) cacc[mt][nt][r] = 0.f;

  // prefetch tile 0
  float4 h0, h1, l0, l1, v0, v1;
  {
    const size_t kb = ((size_t)bh * S_ + srow) * DK_ + sseg * 16;
    const size_t vb = ((size_t)bh * DK_ + srow) * S_ + sseg * 16;
    h0 = *(const float4*)&Kh_[kb]; h1 = *(const float4*)&Kh_[kb + 8];
    l0 = *(const float4*)&Kl_[kb]; l1 = *(const float4*)&Kl_[kb + 8];
    v0 = *(const float4*)&VT[vb];  v1 = *(const float4*)&VT[vb + 8];
  }

  for (int kt = 0; kt < S_; kt += 64) {
    __syncthreads();
    *(float4*)&Ksh[srow * KSTR + sseg * 16] = h0;
    *(float4*)&Ksh[srow * KSTR + sseg * 16 + 8] = h1;
    *(float4*)&Ksl[srow * KSTR + sseg * 16] = l0;
    *(float4*)&Ksl[srow * KSTR + sseg * 16 + 8] = l1;
    *(float4*)&Vs[srow * KSTR + sseg * 16] = v0;
    *(float4*)&Vs[srow * KSTR + sseg * 16 + 8] = v1;
    __syncthreads();

    // mask, transposed order: entry (q = q0w+l31, kv = kt + t*32 + g*8 + 4*kh + i)
    f4 mk[2][4];
#pragma unroll
    for (int t = 0; t < 2; t++)
#pragma unroll
      for (int g = 0; g < 4; g++)
        mk[t][g] = *(const f4*)&mask[(size_t)(q0w + l31) * S_ + kt + t * 32 + g * 8 + 4 * kh];

    // prefetch next tile
    if (kt + 64 < S_) {
      const size_t kb = ((size_t)bh * S_ + kt + 64 + srow) * DK_ + sseg * 16;
      const size_t vb = ((size_t)bh * DK_ + srow) * S_ + kt + 64 + sseg * 16;
      h0 = *(const float4*)&Kh_[kb]; h1 = *(const float4*)&Kh_[kb + 8];
      l0 = *(const float4*)&Kl_[kb]; l1 = *(const float4*)&Kl_[kb + 8];
      v0 = *(const float4*)&VT[vb];  v1 = *(const float4*)&VT[vb + 8];
    }

    // ---- z^T = K·Q^T, 32x32x16 split-3: 16 b128 reads, 24 MFMAs, 32 q ----
    f16v z[2];
#pragma unroll
    for (int t = 0; t < 2; t++)
#pragma unroll
      for (int r = 0; r < 16; r++) z[t][r] = 0.f;
#pragma unroll
    for (int t = 0; t < 2; t++)
#pragma unroll
      for (int ks = 0; ks < 4; ks++) {
        bfrag kbh = *(bfrag*)&Ksh[(t * 32 + l31) * KSTR + ks * 16 + kh * 8];
        bfrag kbl = *(bfrag*)&Ksl[(t * 32 + l31) * KSTR + ks * 16 + kh * 8];
        z[t] = MFMA32(kbh, qhf[ks], z[t]);
        z[t] = MFMA32(kbl, qhf[ks], z[t]);
        z[t] = MFMA32(kbh, qlf[ks], z[t]);
      }

    // ---- scale + mask in place ----
#pragma unroll
    for (int t = 0; t < 2; t++)
#pragma unroll
      for (int r = 0; r < 16; r++)
        z[t][r] = fmaf(z[t][r], SCALE, mk[t][r >> 2][r & 3]);

    // ---- online softmax: per-lane q column, 1 cross-lane reduce ----
    float tm = z[0][0];
#pragma unroll
    for (int t = 0; t < 2; t++)
#pragma unroll
      for (int r = 0; r < 16; r++) tm = fmaxf(tm, z[t][r]);
    tm = fmaxf(tm, __shfl_xor(tm, 32, 64));
    const float nm = fmaxf(m, tm);
    const float al = __expf(m - nm);
    m = nm;
    if (lane < 32) als[wv * 32 + lane] = al;

    float ls = 0.f;
#pragma unroll
    for (int t = 0; t < 2; t++)
#pragma unroll
      for (int g = 0; g < 4; g++) {
        const float e0 = __expf(z[t][g * 4 + 0] - nm);
        const float e1 = __expf(z[t][g * 4 + 1] - nm);
        const float e2 = __expf(z[t][g * 4 + 2] - nm);
        const float e3 = __expf(z[t][g * 4 + 3] - nm);
        ls += (e0 + e1) + (e2 + e3);
        b4 pk;
        pk[0] = (__bf16)e0; pk[1] = (__bf16)e1;
        pk[2] = (__bf16)e2; pk[3] = (__bf16)e3;
        *(b4*)&Ps[(wv * 32 + l31) * PSTR + t * 32 + g * 8 + 4 * kh] = pk;
      }
    l = l * al + ls;

    if (lane < 32)
      MT[((size_t)bh * 32 + (kt >> 6)) * S_ + q0w + lane] = m;

    // ---- rescale cacc with alpha from LDS (row q = mt*16 + qd*4 + r) ----
#pragma unroll
    for (int mt = 0; mt < 2; mt++) {
      f4 av = *(f4*)&als[wv * 32 + mt * 16 + qd * 4];
#pragma unroll
      for (int nt = 0; nt < 4; nt++)
#pragma unroll
        for (int r = 0; r < 4; r++) cacc[mt][nt][r] *= av[r];
    }

    // ---- PV (16 MFMA, 16-shape): P m=q (2 tiles), V n=d (4 tiles), k=kv ----
    bfrag pa[2][2];
#pragma unroll
    for (int mt = 0; mt < 2; mt++)
#pragma unroll
      for (int ks = 0; ks < 2; ks++)
        pa[mt][ks] = *(bfrag*)&Ps[(wv * 32 + mt * 16 + ln) * PSTR + ks * 32 + qd * 8];
#pragma unroll
    for (int nt = 0; nt < 4; nt++)
#pragma unroll
      for (int ks = 0; ks < 2; ks++) {
        bfrag vbf = *(bfrag*)&Vs[(nt * 16 + ln) * KSTR + ks * 32 + qd * 8];
#pragma unroll
        for (int mt = 0; mt < 2; mt++)
          cacc[mt][nt] = MFMA16(pa[mt][ks], vbf, cacc[mt][nt]);
      }

    // ---- E copy: Ps rows -> global fp8 e4m3 (vectorized, coalesced) ----
#pragma unroll
    for (int c = 0; c < 4; c++) {
      const int row = wv * 32 + (lane >> 3) + c * 8;
      const int ch = lane & 7;
      bfrag pv = *(bfrag*)&Ps[row * PSTR + ch * 8];
      int lo = 0, hi = 0;
      lo = __builtin_amdgcn_cvt_pk_fp8_f32((float)pv[0], (float)pv[1], lo, 0);
      lo = __builtin_amdgcn_cvt_pk_fp8_f32((float)pv[2], (float)pv[3], lo, 1);
      hi = __builtin_amdgcn_cvt_pk_fp8_f32((float)pv[4], (float)pv[5], hi, 0);
      hi = __builtin_amdgcn_cvt_pk_fp8_f32((float)pv[6], (float)pv[7], hi, 1);
      u2 ev;
      ev.x = (unsigned int)lo;
      ev.y = (unsigned int)hi;
      __builtin_nontemporal_store(
          ev, (u2*)&E[((size_t)bh * S_ + q0b + row) * S_ + kt + ch * 8]);
    }
  }

  // ---- epilogue ----
  l += __shfl_xor(l, 32, 64);
  if (lane < 32) {
    MR[(size_t)bh * S_ + q0w + lane] = m;
    LR[(size_t)bh * S_ + q0w + lane] = l;
    als[wv * 32 + lane] = 1.0f / l;
  }
  const int b = bh >> 3, h = bh & 7;
#pragma unroll
  for (int mt = 0; mt < 2; mt++) {
    f4 iv = *(f4*)&als[wv * 32 + mt * 16 + qd * 4];
#pragma unroll
    for (int nt = 0; nt < 4; nt++)
#pragma unroll
      for (int r = 0; r < 4; r++)
        CTXb[((size_t)b * S_ + q0w + mt * 16 + qd * 4 + r) * D_ + h * DK_ + nt * 16 + ln] =
            (__bf16)(cacc[mt][nt][r] * iv[r]);
  }
}

// ---------------------------------------------------------------------------
// mean = (1/8) sum_h E * exp(MT - m_fin) / l_fin  — bandwidth kernel.
// E is fp8 e4m3 now: read halves vs bf16; hw cvt_pk_f32_fp8 unpack.
// ---------------------------------------------------------------------------
__global__ __launch_bounds__(256) void mean_rescale(
    const unsigned char* __restrict__ E, const float* __restrict__ MT,
    const float* __restrict__ MR, const float* __restrict__ LR,
    float* __restrict__ meanout) {
  const int t = threadIdx.x;
  const int qr = t >> 3, seg = t & 7;
  const int b = blockIdx.y, ks = blockIdx.z;
  const int qg = blockIdx.x * 32 + qr;

  float mf[H_], il[H_];
#pragma unroll
  for (int h = 0; h < H_; h++) {
    const int bh = b * H_ + h;
    mf[h] = MR[(size_t)bh * S_ + qg];
    il[h] = 1.0f / LR[(size_t)bh * S_ + qg];
  }

  for (int kc = 0; kc < 8; kc++) {
    const int k0 = ks * 512 + kc * 64;
    const int tk = k0 >> 6;
    float acc[8];
#pragma unroll
    for (int j = 0; j < 8; j++) acc[j] = 0.f;
#pragma unroll
    for (int h = 0; h < H_; h++) {
      const int bh = b * H_ + h;
      const float mt = MT[((size_t)bh * 32 + tk) * S_ + qg];
      const float sc = __expf(mt - mf[h]) * il[h];
      u2 e = __builtin_nontemporal_load(
          (const u2*)&E[((size_t)bh * S_ + qg) * S_ + k0 + seg * 8]);
      f2 p01 = __builtin_amdgcn_cvt_pk_f32_fp8((int)e.x, 0);
      f2 p23 = __builtin_amdgcn_cvt_pk_f32_fp8((int)e.x, 1);
      f2 p45 = __builtin_amdgcn_cvt_pk_f32_fp8((int)e.y, 0);
      f2 p67 = __builtin_amdgcn_cvt_pk_f32_fp8((int)e.y, 1);
      acc[0] += p01.x * sc; acc[1] += p01.y * sc;
      acc[2] += p23.x * sc; acc[3] += p23.y * sc;
      acc[4] += p45.x * sc; acc[5] += p45.y * sc;
      acc[6] += p67.x * sc; acc[7] += p67.y * sc;
    }
    f4 o0, o1;
    o0[0] = acc[0] * 0.125f; o0[1] = acc[1] * 0.125f;
    o0[2] = acc[2] * 0.125f; o0[3] = acc[3] * 0.125f;
    o1[0] = acc[4] * 0.125f; o1[1] = acc[5] * 0.125f;
    o1[2] = acc[6] * 0.125f; o1[3] = acc[7] * 0.125f;
    float* mp = &meanout[((size_t)b * S_ + qg) * S_ + k0 + seg * 8];
    *(f4*)&mp[0] = o0;
    *(f4*)&mp[4] = o1;
  }
}

// ---------------------------------------------------------------------------
extern "C" void kernel_launch(void* const* d_in, const int* in_sizes, int n_in,
                              void* d_out, int out_size, void* d_ws, size_t ws_size,
                              hipStream_t stream) {
  (void)in_sizes; (void)n_in; (void)out_size; (void)ws_size;
  const float* Zq = (const float*)d_in[0];
  const float* Zkv = (const float*)d_in[1];
  const float* mask = (const float*)d_in[2];
  const float* Wqkv = (const float*)d_in[3];
  const float* Wout = (const float*)d_in[4];

  float* out = (float*)d_out;                // [B,S,D]
  float* mean = out + (size_t)B_ * S_ * D_;  // [B,S,S]

  char* w = (char*)d_ws;
  const size_t WSZ = 512 * 512 * sizeof(__bf16);
  const size_t QSZ = (size_t)B_ * H_ * S_ * DK_ * sizeof(__bf16);
  __bf16* WqTh = (__bf16*)w; w += WSZ;
  __bf16* WqTl = (__bf16*)w; w += WSZ;
  __bf16* WkTh = (__bf16*)w; w += WSZ;
  __bf16* WkTl = (__bf16*)w; w += WSZ;
  __bf16* WvTh = (__bf16*)w; w += WSZ;
  __bf16* WoTh = (__bf16*)w; w += WSZ;
  __bf16* Qh = (__bf16*)w; w += QSZ;
  __bf16* Ql = (__bf16*)w; w += QSZ;
  __bf16* Kh = (__bf16*)w; w += QSZ;
  __bf16* Kl = (__bf16*)w; w += QSZ;
  __bf16* VTh = (__bf16*)w; w += QSZ;
  __bf16* CTXb = (__bf16*)w; w += QSZ;
  float* MR = (float*)w; w += (size_t)B_ * H_ * S_ * sizeof(float);
  float* LR = (float*)w; w += (size_t)B_ * H_ * S_ * sizeof(float);
  float* MT = (float*)w; w += (size_t)B_ * H_ * 32 * S_ * sizeof(float);       // 8.4 MB
  unsigned char* E = (unsigned char*)w; w += (size_t)B_ * H_ * S_ * S_;        // 134 MB (fp8)

  wtr_all<<<dim3(1024, 4), 256, 0, stream>>>(Wqkv, Wout, WqTh, WqTl, WkTh, WkTl, WvTh, WoTh);

  gemm_mfma<true, false, true, 1><<<dim3(8, 128), 256, 0, stream>>>(
      Zq, WqTh, WqTl, nullptr, Qh, Ql);
  gemm_mfma<true, false, true, 1><<<dim3(8, 128), 256, 0, stream>>>(
      Zkv, WkTh, WkTl, nullptr, Kh, Kl);
  gemm_mfma<false, true, false, 2><<<dim3(128, 8), 256, 0, stream>>>(
      WvTh, Zkv, nullptr, nullptr, VTh, nullptr);

  attn_fctx<<<dim3(16, 32), 256, 0, stream>>>(Qh, Ql, Kh, Kl, VTh, mask, CTXb, MR, LR, E, MT);
  mean_rescale<<<dim3(64, 4, 4), 256, 0, stream>>>(E, MT, MR, LR, mean);

  gemm_mfma<false, false, false, 0><<<dim3(8, 128), 256, 0, stream>>>(
      CTXb, WoTh, nullptr, out, nullptr, nullptr);
}